// Round 7
// baseline (759.800 us; speedup 1.0000x reference)
//
#include <hip/hip_runtime.h>
#include <math.h>
#include <float.h>

// Problem constants (from reference)
#define NB 2
#define LQ 2048
#define HH 8
#define EE 64
#define SS 2048
#define CC 256
#define KM_ITERS 10
#define NBITS 32
#define TK 32
#define NH (NB*HH)
#define CG 4    // clusters per k_rows block

// ---------------- K1: hash bits -> 32-bit mask per (n,h,l) ----------------
__global__ __launch_bounds__(256) void k_hash(const float* __restrict__ Q,
                                              const float* __restrict__ planes,
                                              unsigned int* __restrict__ qmask) {
    int gid = blockIdx.x * 256 + threadIdx.x;      // nh*LQ + l
    int nh = gid >> 11, l = gid & (LQ - 1);
    int n = nh >> 3, h = nh & 7;
    const float* qrow = Q + (((size_t)n * LQ + l) * HH + h) * EE;
    float q[64];
    #pragma unroll
    for (int e = 0; e < 64; e++) q[e] = qrow[e];
    unsigned int m = 0;
    for (int b = 0; b < NBITS; b++) {
        double acc = (double)planes[b * 65 + 64];   // bias
        #pragma unroll
        for (int e = 0; e < 64; e++) acc += (double)q[e] * (double)planes[b * 65 + e];
        if (acc > 0.0) m |= (1u << b);
    }
    qmask[gid] = m;
}

// ---------------- K2a: centroid init ----------------
__global__ __launch_bounds__(256) void k_cinit(const unsigned int* __restrict__ qmask,
                                               unsigned int* __restrict__ cent_g) {
    int nh = blockIdx.x, t = threadIdx.x;
    cent_g[nh * CC + t] = qmask[(size_t)nh * LQ + t * 8];   // init_idx = c*8
}

// ---------------- K2b: assign (data-parallel, 128 blocks) ----------------
// dist packed as (d<<8)|c; integer min == first-min tie-break of jnp.argmin.
__global__ __launch_bounds__(256) void k_assign(const unsigned int* __restrict__ qmask,
                                                const unsigned int* __restrict__ cent_g,
                                                int* __restrict__ asg) {
    int nh = blockIdx.x >> 3;              // 8 blocks per nh
    int p = ((blockIdx.x & 7) << 8) + threadIdx.x;
    int t = threadIdx.x;
    __shared__ __align__(16) unsigned int cent[CC];
    cent[t] = cent_g[nh * CC + t];
    __syncthreads();
    unsigned int m = qmask[(size_t)nh * LQ + p];
    int best = 0x7fffffff;
    const uint4* c4p = (const uint4*)cent;
    #pragma unroll 4
    for (int c4 = 0; c4 < CC / 4; c4++) {
        uint4 cm = c4p[c4];
        int base = c4 << 2;
        int e0 = (__popc(m ^ cm.x) << 8) + base;
        int e1 = (__popc(m ^ cm.y) << 8) + base + 1;
        int e2 = (__popc(m ^ cm.z) << 8) + base + 2;
        int e3 = (__popc(m ^ cm.w) << 8) + base + 3;
        int e01 = e0 < e1 ? e0 : e1;
        int e23 = e2 < e3 ? e2 : e3;
        int e = e01 < e23 ? e01 : e23;
        best = best < e ? best : e;
    }
    asg[(size_t)nh * LQ + p] = best & 255;
}

// ---------------- K2c: update (per-nh counting sort + exact majority) ----------------
__global__ __launch_bounds__(512) void k_update(const unsigned int* __restrict__ qmask,
                                                const int* __restrict__ asg,
                                                unsigned int* __restrict__ cent_g) {
    int nh = blockIdx.x, t = threadIdx.x;
    __shared__ unsigned int sorted[LQ];               // 8KB
    __shared__ int cnts[CC], offs[CC], cursor[CC];
    if (t < CC) cnts[t] = 0;
    int bc[4]; unsigned int mym[4];
    #pragma unroll
    for (int k = 0; k < 4; k++) {
        bc[k] = asg[(size_t)nh * LQ + t + k * 512];
        mym[k] = qmask[(size_t)nh * LQ + t + k * 512];
    }
    __syncthreads();
    #pragma unroll
    for (int k = 0; k < 4; k++) atomicAdd(&cnts[bc[k]], 1);
    __syncthreads();
    if (t < 64) {                                     // single-wave exclusive scan
        int c0 = cnts[4 * t], c1 = cnts[4 * t + 1], c2 = cnts[4 * t + 2], c3 = cnts[4 * t + 3];
        int s1 = c0 + c1, s2 = s1 + c2, tot = s2 + c3;
        int inc = tot;
        #pragma unroll
        for (int o = 1; o < 64; o <<= 1) {
            int v = __shfl_up(inc, o);
            if (t >= o) inc += v;
        }
        int excl = inc - tot;
        offs[4 * t] = excl;          cursor[4 * t] = excl;
        offs[4 * t + 1] = excl + c0; cursor[4 * t + 1] = excl + c0;
        offs[4 * t + 2] = excl + s1; cursor[4 * t + 2] = excl + s1;
        offs[4 * t + 3] = excl + s2; cursor[4 * t + 3] = excl + s2;
    }
    __syncthreads();
    int cl = t >> 1, j = t & 1;
    int cnt_c = cnts[cl], off_c = offs[cl];
    #pragma unroll
    for (int k = 0; k < 4; k++) {
        int pos = atomicAdd(&cursor[bc[k]], 1);
        sorted[pos] = mym[k];
    }
    __syncthreads();
    int bs[32];
    #pragma unroll
    for (int b = 0; b < 32; b++) bs[b] = 0;
    for (int i = j; i < cnt_c; i += 2) {
        unsigned int m = sorted[off_c + i];
        #pragma unroll
        for (int b = 0; b < 32; b++) bs[b] += (m >> b) & 1;
    }
    #pragma unroll
    for (int b = 0; b < 32; b++) bs[b] += __shfl_xor(bs[b], 1);
    if (j == 0 && cnt_c > 0) {
        unsigned int nc = 0;
        #pragma unroll
        for (int b = 0; b < 32; b++) if (2 * bs[b] >= cnt_c) nc |= (1u << b);
        cent_g[nh * CC + cl] = nc;                    // exact majority; keep old if cnt==0
    }
}

// ---------------- K2d: finalize counts/offsets/order from final assignment ----------------
__global__ __launch_bounds__(512) void k_finalize(const int* __restrict__ asg,
                                                  int* __restrict__ counts_out,
                                                  int* __restrict__ order_out,
                                                  int* __restrict__ offsets_out) {
    int nh = blockIdx.x, t = threadIdx.x;
    __shared__ int cnts[CC], offs[CC], cursor[CC];
    if (t < CC) cnts[t] = 0;
    int bc[4];
    #pragma unroll
    for (int k = 0; k < 4; k++) bc[k] = asg[(size_t)nh * LQ + t + k * 512];
    __syncthreads();
    #pragma unroll
    for (int k = 0; k < 4; k++) atomicAdd(&cnts[bc[k]], 1);
    __syncthreads();
    if (t < 64) {
        int c0 = cnts[4 * t], c1 = cnts[4 * t + 1], c2 = cnts[4 * t + 2], c3 = cnts[4 * t + 3];
        int s1 = c0 + c1, s2 = s1 + c2, tot = s2 + c3;
        int inc = tot;
        #pragma unroll
        for (int o = 1; o < 64; o <<= 1) {
            int v = __shfl_up(inc, o);
            if (t >= o) inc += v;
        }
        int excl = inc - tot;
        offs[4 * t] = excl;          cursor[4 * t] = excl;
        offs[4 * t + 1] = excl + c0; cursor[4 * t + 1] = excl + c0;
        offs[4 * t + 2] = excl + s1; cursor[4 * t + 2] = excl + s1;
        offs[4 * t + 3] = excl + s2; cursor[4 * t + 3] = excl + s2;
    }
    __syncthreads();
    if (t < CC) {
        counts_out[nh * CC + t] = cnts[t];
        offsets_out[nh * CC + t] = offs[t];
    }
    #pragma unroll
    for (int k = 0; k < 4; k++) {
        int pos = atomicAdd(&cursor[bc[k]], 1);
        order_out[(size_t)nh * LQ + pos] = t + k * 512;
    }
}

// ---------------- K3: segmented cluster-mean Qg (f64), wave per cluster ----------------
__global__ __launch_bounds__(256) void k_qg(const float* __restrict__ Q,
                                            const int* __restrict__ order,
                                            const int* __restrict__ offsets,
                                            const int* __restrict__ counts,
                                            double* __restrict__ Qg) {
    int nh = blockIdx.x >> 6;              // 64 blocks per nh
    int c = (blockIdx.x & 63) * 4 + (threadIdx.x >> 6);
    int e = threadIdx.x & 63;
    int n = nh >> 3, h = nh & 7;
    int off = offsets[nh * CC + c];
    int cnt = counts[nh * CC + c];
    const int* ord = order + (size_t)nh * LQ + off;
    double acc = 0.0;
    for (int i = 0; i < cnt; i++) {
        int p = ord[i];                    // wave-uniform broadcast read
        acc += (double)Q[(((size_t)n * LQ + p) * HH + h) * EE + e];
    }
    double safe = cnt > 0 ? (double)cnt : 1.0;
    Qg[((size_t)(nh * CC + c)) * EE + e] = acc / safe;
}

// ---------------- K3b: transpose [n][s][h][e] -> [nh][e][s] ----------------
__global__ __launch_bounds__(256) void k_transpose(const float* __restrict__ Xp,
                                                   float* __restrict__ Xt) {
    int nh = blockIdx.x >> 5;              // 32 s-tiles of 64
    int s0 = (blockIdx.x & 31) * 64;
    int n = nh >> 3, h = nh & 7;
    __shared__ float tile[64][65];
    int t = threadIdx.x;
    int e = t & 63, r0 = t >> 6;
    #pragma unroll
    for (int j = 0; j < 16; j++) {
        int r = r0 * 16 + j;
        tile[r][e] = Xp[(((size_t)n * SS + s0 + r) * HH + h) * EE + e];
    }
    __syncthreads();
    int sl = t & 63, eg = t >> 6;
    #pragma unroll
    for (int j = 0; j < 16; j++) {
        int ee_ = eg * 16 + j;
        Xt[((size_t)nh * EE + ee_) * SS + s0 + sl] = tile[sl][ee_];
    }
}

// ---------------- K4 v3: wave-per-cluster, all-register scores/top-k/weights ----------------
// lane l owns s = l*32+k (k=0..31). Phase A: f64 scores in regs (same e-order dot
// as reference -> bit-identical per-score values). Phase B: in-register top-32,
// packed (value,index) compares, ties -> lowest s. Phase C: weights in regs x Vt.
__global__ __launch_bounds__(256, 4) void k_rows(const float* __restrict__ Kt,
                                                 const float* __restrict__ Vt,
                                                 const double* __restrict__ Qg,
                                                 int* __restrict__ topi,
                                                 float* __restrict__ abk,
                                                 float* __restrict__ Vg) {
    int bid = blockIdx.x;
    // XCD-chunked swizzle (1024 blocks, 8 XCDs): xcd owns 2 nh slices -> L2 locality
    int xcd = bid & 7, idx = bid >> 3;     // idx 0..127
    int nh = xcd * 2 + (idx >> 6);
    int cg = idx & 63;
    int c0 = cg * CG;
    int t = threadIdx.x, w = t >> 6, l = t & 63;

    __shared__ double qgl[EE][CG];         // 2KB
    __shared__ float pred[CG][EE][17];     // 17.4KB, padded 17 -> conflict-free

    qgl[t >> 2][t & 3] = Qg[((size_t)(nh * CC + c0 + (t & 3))) * EE + (t >> 2)];
    __syncthreads();

    // ---- phase A: v[k] = score(c0+w, s=l*32+k), f64 register accumulate ----
    double v[32];
    #pragma unroll
    for (int k = 0; k < 32; k++) v[k] = 0.0;
    const float* ktb = Kt + ((size_t)nh * EE) * SS + l * 32;
    for (int e = 0; e < EE; e++) {
        double qe = qgl[e][w];
        const float4* kr = (const float4*)(ktb + (size_t)e * SS);
        #pragma unroll
        for (int j = 0; j < 8; j++) {
            float4 kv = kr[j];
            v[4 * j + 0] += qe * (double)kv.x;
            v[4 * j + 1] += qe * (double)kv.y;
            v[4 * j + 2] += qe * (double)kv.z;
            v[4 * j + 3] += qe * (double)kv.w;
        }
    }

    // ---- phase B: max, denom, top-32 (in-register), weights ----
    double m = v[0];
    #pragma unroll
    for (int k = 1; k < 32; k++) m = v[k] > m ? v[k] : m;
    #pragma unroll
    for (int o = 32; o > 0; o >>= 1) { double z = __shfl_xor(m, o); m = z > m ? z : m; }

    double ds = 0.0;
    #pragma unroll
    for (int k = 0; k < 32; k++) ds += (double)expf(0.125f * (float)(v[k] - m));
    #pragma unroll
    for (int o = 32; o > 0; o >>= 1) ds += __shfl_xor(ds, o);

    unsigned ext = 0u;
    double lbv = -1e301; int lbi = 1 << 30;
    #pragma unroll
    for (int k = 0; k < 32; k++)
        if (v[k] > lbv) { lbv = v[k]; lbi = l * 32 + k; }
    double topsum = 0.0;
    int rowid = nh * CC + c0 + w;
    for (int kk = 0; kk < TK; kk++) {
        double bv = lbv; int bi = lbi;
        #pragma unroll
        for (int o = 32; o > 0; o >>= 1) {
            double v2 = __shfl_xor(bv, o); int i2 = __shfl_xor(bi, o);
            if (v2 > bv || (v2 == bv && i2 < bi)) { bv = v2; bi = i2; }
        }
        topsum += (double)expf(0.125f * (float)(bv - m));
        if (l == 0) topi[(size_t)rowid * TK + kk] = bi;
        if ((bi >> 5) == l) {              // this lane owned the winner
            ext |= 1u << (bi & 31);
            lbv = -1e301; lbi = 1 << 30;
            #pragma unroll
            for (int k = 0; k < 32; k++)
                if (!((ext >> k) & 1) && v[k] > lbv) { lbv = v[k]; lbi = l * 32 + k; }
        }
    }
    if (l == 0) abk[rowid] = (float)((ds - topsum) / ds);

    float invd = (float)(1.0 / ds);
    float w32[32];
    #pragma unroll
    for (int k = 0; k < 32; k++)
        w32[k] = ((ext >> k) & 1) ? 0.0f
               : expf(0.125f * (float)(v[k] - m)) * invd;

    // ---- phase C: Vg[c][e] = sum_s w[s]*V[s][e], weights in regs, Vt coalesced ----
    const float* vtb = Vt + ((size_t)nh * EE) * SS + l * 32;
    for (int e = 0; e < EE; e++) {
        const float4* vr = (const float4*)(vtb + (size_t)e * SS);
        float a0 = 0.f, a1 = 0.f, a2 = 0.f, a3 = 0.f;
        #pragma unroll
        for (int j = 0; j < 8; j += 4) {
            float4 v0 = vr[j], v1 = vr[j + 1], v2 = vr[j + 2], v3 = vr[j + 3];
            a0 += w32[4 * j + 0] * v0.x + w32[4 * j + 1] * v0.y + w32[4 * j + 2] * v0.z + w32[4 * j + 3] * v0.w;
            a1 += w32[4 * j + 4] * v1.x + w32[4 * j + 5] * v1.y + w32[4 * j + 6] * v1.z + w32[4 * j + 7] * v1.w;
            a2 += w32[4 * j + 8] * v2.x + w32[4 * j + 9] * v2.y + w32[4 * j + 10] * v2.z + w32[4 * j + 11] * v2.w;
            a3 += w32[4 * j + 12] * v3.x + w32[4 * j + 13] * v3.y + w32[4 * j + 14] * v3.z + w32[4 * j + 15] * v3.w;
        }
        float acc = (a0 + a1) + (a2 + a3);
        acc += __shfl_xor(acc, 16);
        acc += __shfl_xor(acc, 32);
        if (l < 16) pred[w][e][l] = acc;   // 16 coset sums per (c,e)
    }
    __syncthreads();
    {
        int c = t >> 6, e = t & 63;
        float s = 0.f;
        #pragma unroll
        for (int i = 0; i < 16; i++) s += pred[c][e][i];
        Vg[((size_t)(nh * CC + c0 + c)) * EE + e] = s;
    }
}

// ---------------- K5: per-query top-32 re-attention + V_bottom ----------------
__global__ __launch_bounds__(256) void k_out(const float* __restrict__ Q,
                                             const float* __restrict__ Kp,
                                             const float* __restrict__ Vp,
                                             const int* __restrict__ clusters,
                                             const int* __restrict__ topi,
                                             const float* __restrict__ abk,
                                             const float* __restrict__ Vg,
                                             float* __restrict__ out) {
    int tid = threadIdx.x, wid = tid >> 6, e = tid & 63;
    int q = blockIdx.x * 4 + wid;            // nh*LQ + l
    int nh = q >> 11, l = q & (LQ - 1);
    int n = nh >> 3, h = nh & 7;
    int c = clusters[q];
    float scale = 1.0f - abk[nh * CC + c];
    const int* ti = topi + (size_t)(nh * CC + c) * TK;
    float qe = Q[(((size_t)n * LQ + l) * HH + h) * EE + e];
    float myv = -INFINITY;
    for (int k = 0; k < TK; k++) {
        int idx = ti[k];
        float kv = Kp[(((size_t)n * SS + idx) * HH + h) * EE + e];
        float v = qe * kv;
        #pragma unroll
        for (int o = 32; o > 0; o >>= 1) v += __shfl_xor(v, o);
        if (e == k) myv = v;
    }
    float mv = myv;
    #pragma unroll
    for (int o = 32; o > 0; o >>= 1) { float v = __shfl_xor(mv, o); mv = v > mv ? v : mv; }
    float p = (e < TK) ? expf(0.125f * (myv - mv)) : 0.0f;
    float ssum = p;
    #pragma unroll
    for (int o = 32; o > 0; o >>= 1) ssum += __shfl_xor(ssum, o);
    float at = p / ssum * scale;
    float acc = 0.0f;
    for (int k = 0; k < TK; k++) {
        float wk = __shfl(at, k, 64);
        int idx = ti[k];
        acc += wk * Vp[(((size_t)n * SS + idx) * HH + h) * EE + e];
    }
    acc += Vg[(size_t)(nh * CC + c) * EE + e];
    out[(((size_t)n * LQ + l) * HH + h) * EE + e] = acc;
}

extern "C" void kernel_launch(void* const* d_in, const int* in_sizes, int n_in,
                              void* d_out, int out_size, void* d_ws, size_t ws_size,
                              hipStream_t stream) {
    const float* Q      = (const float*)d_in[0];
    const float* K      = (const float*)d_in[1];
    const float* V      = (const float*)d_in[2];
    const float* planes = (const float*)d_in[3];
    float* out = (float*)d_out;

    char* ws = (char*)d_ws;
    unsigned int* qmask    = (unsigned int*)(ws);                   // 128KB
    int*          clusters = (int*)(ws + (128 << 10));              // 128KB (= asg)
    int*          counts   = (int*)(ws + (256 << 10));              // 16KB
    float*        abk      = (float*)(ws + (272 << 10));            // 16KB
    int*          topi     = (int*)(ws + (288 << 10));              // 512KB
    float*        Vg       = (float*)(ws + (800 << 10));            // 1MB
    double*       Qg       = (double*)(ws + (1824 << 10));          // 2MB
    float*        Kt       = (float*)(ws + (4096 << 10));           // 8MB  [4MB,12MB)
    int*          order    = (int*)(ws + (12288 << 10));            // 128KB
    int*          offsets  = (int*)(ws + (12416 << 10));            // 16KB
    unsigned int* cent_g   = (unsigned int*)(ws + (12432 << 10));   // 16KB
    float*        Vt       = (float*)(ws + (12544 << 10));          // 8MB [12.25MB,20.25MB)

    k_transpose<<<dim3(NH * 32), dim3(256), 0, stream>>>(K, Kt);
    k_transpose<<<dim3(NH * 32), dim3(256), 0, stream>>>(V, Vt);
    k_hash<<<dim3(NH * LQ / 256), dim3(256), 0, stream>>>(Q, planes, qmask);
    k_cinit<<<dim3(NH), dim3(256), 0, stream>>>(qmask, cent_g);
    for (int it = 0; it < KM_ITERS; ++it) {
        k_assign<<<dim3(NH * 8), dim3(256), 0, stream>>>(qmask, cent_g, clusters);
        k_update<<<dim3(NH), dim3(512), 0, stream>>>(qmask, clusters, cent_g);
    }
    k_assign<<<dim3(NH * 8), dim3(256), 0, stream>>>(qmask, cent_g, clusters);
    k_finalize<<<dim3(NH), dim3(512), 0, stream>>>(clusters, counts, order, offsets);
    k_qg<<<dim3(NH * 64), dim3(256), 0, stream>>>(Q, order, offsets, counts, Qg);
    k_rows<<<dim3(NH * CC / CG), dim3(256), 0, stream>>>(Kt, Vt, Qg, topi, abk, Vg);
    k_out<<<dim3(NH * LQ / 4), dim3(256), 0, stream>>>(Q, K, V, clusters, topi, abk, Vg, out);
}

// Round 8
// 468.456 us; speedup vs baseline: 1.6219x; 1.6219x over previous
//
#include <hip/hip_runtime.h>
#include <math.h>
#include <float.h>

// Problem constants (from reference)
#define NB 2
#define LQ 2048
#define HH 8
#define EE 64
#define SS 2048
#define CC 256
#define KM_ITERS 10
#define NBITS 32
#define TK 32
#define NH (NB*HH)
#define CG 4    // clusters per k_rows block

// ---------------- K1: hash bits -> 32-bit mask per (n,h,l) ----------------
__global__ __launch_bounds__(256) void k_hash(const float* __restrict__ Q,
                                              const float* __restrict__ planes,
                                              unsigned int* __restrict__ qmask) {
    int gid = blockIdx.x * 256 + threadIdx.x;      // nh*LQ + l
    int nh = gid >> 11, l = gid & (LQ - 1);
    int n = nh >> 3, h = nh & 7;
    const float* qrow = Q + (((size_t)n * LQ + l) * HH + h) * EE;
    float q[64];
    #pragma unroll
    for (int e = 0; e < 64; e++) q[e] = qrow[e];
    unsigned int m = 0;
    for (int b = 0; b < NBITS; b++) {
        double acc = (double)planes[b * 65 + 64];   // bias
        #pragma unroll
        for (int e = 0; e < 64; e++) acc += (double)q[e] * (double)planes[b * 65 + e];
        if (acc > 0.0) m |= (1u << b);
    }
    qmask[gid] = m;
}

// ---------------- K2a: centroid init ----------------
__global__ __launch_bounds__(256) void k_cinit(const unsigned int* __restrict__ qmask,
                                               unsigned int* __restrict__ cent_g) {
    int nh = blockIdx.x, t = threadIdx.x;
    cent_g[nh * CC + t] = qmask[(size_t)nh * LQ + t * 8];   // init_idx = c*8
}

// ---------------- K2b: assign (data-parallel, 128 blocks) ----------------
// dist packed as (d<<8)|c; integer min == first-min tie-break of jnp.argmin.
__global__ __launch_bounds__(256) void k_assign(const unsigned int* __restrict__ qmask,
                                                const unsigned int* __restrict__ cent_g,
                                                int* __restrict__ asg) {
    int nh = blockIdx.x >> 3;              // 8 blocks per nh
    int p = ((blockIdx.x & 7) << 8) + threadIdx.x;
    int t = threadIdx.x;
    __shared__ __align__(16) unsigned int cent[CC];
    cent[t] = cent_g[nh * CC + t];
    __syncthreads();
    unsigned int m = qmask[(size_t)nh * LQ + p];
    int best = 0x7fffffff;
    const uint4* c4p = (const uint4*)cent;
    #pragma unroll 4
    for (int c4 = 0; c4 < CC / 4; c4++) {
        uint4 cm = c4p[c4];
        int base = c4 << 2;
        int e0 = (__popc(m ^ cm.x) << 8) + base;
        int e1 = (__popc(m ^ cm.y) << 8) + base + 1;
        int e2 = (__popc(m ^ cm.z) << 8) + base + 2;
        int e3 = (__popc(m ^ cm.w) << 8) + base + 3;
        int e01 = e0 < e1 ? e0 : e1;
        int e23 = e2 < e3 ? e2 : e3;
        int e = e01 < e23 ? e01 : e23;
        best = best < e ? best : e;
    }
    asg[(size_t)nh * LQ + p] = best & 255;
}

// ---------------- K2c: update (per-nh counting sort + exact majority) ----------------
__global__ __launch_bounds__(512) void k_update(const unsigned int* __restrict__ qmask,
                                                const int* __restrict__ asg,
                                                unsigned int* __restrict__ cent_g) {
    int nh = blockIdx.x, t = threadIdx.x;
    __shared__ unsigned int sorted[LQ];               // 8KB
    __shared__ int cnts[CC], offs[CC], cursor[CC];
    if (t < CC) cnts[t] = 0;
    int bc[4]; unsigned int mym[4];
    #pragma unroll
    for (int k = 0; k < 4; k++) {
        bc[k] = asg[(size_t)nh * LQ + t + k * 512];
        mym[k] = qmask[(size_t)nh * LQ + t + k * 512];
    }
    __syncthreads();
    #pragma unroll
    for (int k = 0; k < 4; k++) atomicAdd(&cnts[bc[k]], 1);
    __syncthreads();
    if (t < 64) {                                     // single-wave exclusive scan
        int c0 = cnts[4 * t], c1 = cnts[4 * t + 1], c2 = cnts[4 * t + 2], c3 = cnts[4 * t + 3];
        int s1 = c0 + c1, s2 = s1 + c2, tot = s2 + c3;
        int inc = tot;
        #pragma unroll
        for (int o = 1; o < 64; o <<= 1) {
            int v = __shfl_up(inc, o);
            if (t >= o) inc += v;
        }
        int excl = inc - tot;
        offs[4 * t] = excl;          cursor[4 * t] = excl;
        offs[4 * t + 1] = excl + c0; cursor[4 * t + 1] = excl + c0;
        offs[4 * t + 2] = excl + s1; cursor[4 * t + 2] = excl + s1;
        offs[4 * t + 3] = excl + s2; cursor[4 * t + 3] = excl + s2;
    }
    __syncthreads();
    int cl = t >> 1, j = t & 1;
    int cnt_c = cnts[cl], off_c = offs[cl];
    #pragma unroll
    for (int k = 0; k < 4; k++) {
        int pos = atomicAdd(&cursor[bc[k]], 1);
        sorted[pos] = mym[k];
    }
    __syncthreads();
    int bs[32];
    #pragma unroll
    for (int b = 0; b < 32; b++) bs[b] = 0;
    for (int i = j; i < cnt_c; i += 2) {
        unsigned int m = sorted[off_c + i];
        #pragma unroll
        for (int b = 0; b < 32; b++) bs[b] += (m >> b) & 1;
    }
    #pragma unroll
    for (int b = 0; b < 32; b++) bs[b] += __shfl_xor(bs[b], 1);
    if (j == 0 && cnt_c > 0) {
        unsigned int nc = 0;
        #pragma unroll
        for (int b = 0; b < 32; b++) if (2 * bs[b] >= cnt_c) nc |= (1u << b);
        cent_g[nh * CC + cl] = nc;                    // exact majority; keep old if cnt==0
    }
}

// ---------------- K2d: finalize counts/offsets/order from final assignment ----------------
__global__ __launch_bounds__(512) void k_finalize(const int* __restrict__ asg,
                                                  int* __restrict__ counts_out,
                                                  int* __restrict__ order_out,
                                                  int* __restrict__ offsets_out) {
    int nh = blockIdx.x, t = threadIdx.x;
    __shared__ int cnts[CC], offs[CC], cursor[CC];
    if (t < CC) cnts[t] = 0;
    int bc[4];
    #pragma unroll
    for (int k = 0; k < 4; k++) bc[k] = asg[(size_t)nh * LQ + t + k * 512];
    __syncthreads();
    #pragma unroll
    for (int k = 0; k < 4; k++) atomicAdd(&cnts[bc[k]], 1);
    __syncthreads();
    if (t < 64) {
        int c0 = cnts[4 * t], c1 = cnts[4 * t + 1], c2 = cnts[4 * t + 2], c3 = cnts[4 * t + 3];
        int s1 = c0 + c1, s2 = s1 + c2, tot = s2 + c3;
        int inc = tot;
        #pragma unroll
        for (int o = 1; o < 64; o <<= 1) {
            int v = __shfl_up(inc, o);
            if (t >= o) inc += v;
        }
        int excl = inc - tot;
        offs[4 * t] = excl;          cursor[4 * t] = excl;
        offs[4 * t + 1] = excl + c0; cursor[4 * t + 1] = excl + c0;
        offs[4 * t + 2] = excl + s1; cursor[4 * t + 2] = excl + s1;
        offs[4 * t + 3] = excl + s2; cursor[4 * t + 3] = excl + s2;
    }
    __syncthreads();
    if (t < CC) {
        counts_out[nh * CC + t] = cnts[t];
        offsets_out[nh * CC + t] = offs[t];
    }
    #pragma unroll
    for (int k = 0; k < 4; k++) {
        int pos = atomicAdd(&cursor[bc[k]], 1);
        order_out[(size_t)nh * LQ + pos] = t + k * 512;
    }
}

// ---------------- K3: segmented cluster-mean Qg (f64), wave per cluster ----------------
__global__ __launch_bounds__(256) void k_qg(const float* __restrict__ Q,
                                            const int* __restrict__ order,
                                            const int* __restrict__ offsets,
                                            const int* __restrict__ counts,
                                            double* __restrict__ Qg) {
    int nh = blockIdx.x >> 6;              // 64 blocks per nh
    int c = (blockIdx.x & 63) * 4 + (threadIdx.x >> 6);
    int e = threadIdx.x & 63;
    int n = nh >> 3, h = nh & 7;
    int off = offsets[nh * CC + c];
    int cnt = counts[nh * CC + c];
    const int* ord = order + (size_t)nh * LQ + off;
    double acc = 0.0;
    for (int i = 0; i < cnt; i++) {
        int p = ord[i];                    // wave-uniform broadcast read
        acc += (double)Q[(((size_t)n * LQ + p) * HH + h) * EE + e];
    }
    double safe = cnt > 0 ? (double)cnt : 1.0;
    Qg[((size_t)(nh * CC + c)) * EE + e] = acc / safe;
}

// ---------------- K3b: transpose [n][s][h][e] -> [nh][e][s] ----------------
__global__ __launch_bounds__(256) void k_transpose(const float* __restrict__ Xp,
                                                   float* __restrict__ Xt) {
    int nh = blockIdx.x >> 5;              // 32 s-tiles of 64
    int s0 = (blockIdx.x & 31) * 64;
    int n = nh >> 3, h = nh & 7;
    __shared__ float tile[64][65];
    int t = threadIdx.x;
    int e = t & 63, r0 = t >> 6;
    #pragma unroll
    for (int j = 0; j < 16; j++) {
        int r = r0 * 16 + j;
        tile[r][e] = Xp[(((size_t)n * SS + s0 + r) * HH + h) * EE + e];
    }
    __syncthreads();
    int sl = t & 63, eg = t >> 6;
    #pragma unroll
    for (int j = 0; j < 16; j++) {
        int ee_ = eg * 16 + j;
        Xt[((size_t)nh * EE + ee_) * SS + s0 + sl] = tile[sl][ee_];
    }
}

// ---------------- K4 v4: wave-per-cluster, register scores, COALESCED float4 ----------------
// lane l owns s = kb*256 + l*4 + jb (kb=0..7, jb=0..3), v[4*kb+jb].
// Wave float4 load at fixed kb: lanes consecutive -> 1KB coalesced.
// Decisions: f64 scores (same e-order dot as ref), packed (value,s) strict
// compare, ties -> lowest s == lax.top_k set semantics.
__global__ __launch_bounds__(256) void k_rows(const float* __restrict__ Kt,
                                              const float* __restrict__ Vt,
                                              const double* __restrict__ Qg,
                                              int* __restrict__ topi,
                                              float* __restrict__ abk,
                                              float* __restrict__ Vg) {
    int bid = blockIdx.x;
    // XCD-chunked swizzle (1024 blocks, 8 XCDs): xcd owns 2 nh slices -> L2 locality
    int xcd = bid & 7, idx = bid >> 3;     // idx 0..127
    int nh = xcd * 2 + (idx >> 6);
    int cg = idx & 63;
    int c0 = cg * CG;
    int t = threadIdx.x, w = t >> 6, l = t & 63;

    __shared__ double qgl[EE][CG];         // 2KB
    __shared__ float pred[CG][EE][17];     // 17.4KB, padded 17 -> conflict-free

    qgl[t >> 2][t & 3] = Qg[((size_t)(nh * CC + c0 + (t & 3))) * EE + (t >> 2)];
    __syncthreads();

    // ---- phase A: f64 register scores, coalesced float4 Kt reads ----
    double v[32];
    #pragma unroll
    for (int k = 0; k < 32; k++) v[k] = 0.0;
    const float* ktb = Kt + ((size_t)nh * EE) * SS + l * 4;
    for (int e = 0; e < EE; e++) {
        double qe = qgl[e][w];
        const float4* kr = (const float4*)(ktb + (size_t)e * SS);
        #pragma unroll
        for (int kb = 0; kb < 8; kb++) {
            float4 kv = kr[kb * 64];       // addr: l*4 + kb*256 floats
            v[4 * kb + 0] += qe * (double)kv.x;
            v[4 * kb + 1] += qe * (double)kv.y;
            v[4 * kb + 2] += qe * (double)kv.z;
            v[4 * kb + 3] += qe * (double)kv.w;
        }
    }

    // ---- phase B: max, denom, in-register top-32, weights ----
    double m = v[0];
    #pragma unroll
    for (int k = 1; k < 32; k++) m = v[k] > m ? v[k] : m;
    #pragma unroll
    for (int o = 32; o > 0; o >>= 1) { double z = __shfl_xor(m, o); m = z > m ? z : m; }

    double ds = 0.0;
    #pragma unroll
    for (int k = 0; k < 32; k++) ds += (double)expf(0.125f * (float)(v[k] - m));
    #pragma unroll
    for (int o = 32; o > 0; o >>= 1) ds += __shfl_xor(ds, o);

    unsigned ext = 0u;
    double lbv = -1e301; int lbi = 1 << 30;
    #pragma unroll
    for (int k = 0; k < 32; k++)
        if (v[k] > lbv) { lbv = v[k]; lbi = ((k >> 2) << 8) + l * 4 + (k & 3); }
    double topsum = 0.0;
    int rowid = nh * CC + c0 + w;
    for (int kk = 0; kk < TK; kk++) {
        double bv = lbv; int bi = lbi;
        #pragma unroll
        for (int o = 32; o > 0; o >>= 1) {
            double v2 = __shfl_xor(bv, o); int i2 = __shfl_xor(bi, o);
            if (v2 > bv || (v2 == bv && i2 < bi)) { bv = v2; bi = i2; }
        }
        topsum += (double)expf(0.125f * (float)(bv - m));
        if (l == 0) topi[(size_t)rowid * TK + kk] = bi;
        if (((bi >> 2) & 63) == l) {       // this lane owned the winner
            ext |= 1u << (((bi >> 8) << 2) | (bi & 3));
            lbv = -1e301; lbi = 1 << 30;
            #pragma unroll
            for (int k = 0; k < 32; k++)
                if (!((ext >> k) & 1) && v[k] > lbv) { lbv = v[k]; lbi = ((k >> 2) << 8) + l * 4 + (k & 3); }
        }
    }
    if (l == 0) abk[rowid] = (float)((ds - topsum) / ds);

    float invd = (float)(1.0 / ds);
    float w32[32];
    #pragma unroll
    for (int k = 0; k < 32; k++)
        w32[k] = ((ext >> k) & 1) ? 0.0f
               : expf(0.125f * (float)(v[k] - m)) * invd;

    // ---- phase C: Vg[c][e] = sum_s w[s]*V[s][e], coalesced Vt float4 ----
    const float* vtb = Vt + ((size_t)nh * EE) * SS + l * 4;
    for (int e = 0; e < EE; e++) {
        const float4* vr = (const float4*)(vtb + (size_t)e * SS);
        float a0 = 0.f, a1 = 0.f, a2 = 0.f, a3 = 0.f;
        #pragma unroll
        for (int kb = 0; kb < 8; kb += 4) {
            float4 v0 = vr[kb * 64], v1 = vr[(kb + 1) * 64], v2 = vr[(kb + 2) * 64], v3 = vr[(kb + 3) * 64];
            a0 += w32[4 * kb + 0] * v0.x + w32[4 * kb + 1] * v0.y + w32[4 * kb + 2] * v0.z + w32[4 * kb + 3] * v0.w;
            a1 += w32[4 * kb + 4] * v1.x + w32[4 * kb + 5] * v1.y + w32[4 * kb + 6] * v1.z + w32[4 * kb + 7] * v1.w;
            a2 += w32[4 * kb + 8] * v2.x + w32[4 * kb + 9] * v2.y + w32[4 * kb + 10] * v2.z + w32[4 * kb + 11] * v2.w;
            a3 += w32[4 * kb + 12] * v3.x + w32[4 * kb + 13] * v3.y + w32[4 * kb + 14] * v3.z + w32[4 * kb + 15] * v3.w;
        }
        float acc = (a0 + a1) + (a2 + a3);
        acc += __shfl_xor(acc, 16);
        acc += __shfl_xor(acc, 32);
        if (l < 16) pred[w][e][l] = acc;   // 16 coset sums per (c,e)
    }
    __syncthreads();
    {
        int c = t >> 6, e = t & 63;
        float s = 0.f;
        #pragma unroll
        for (int i = 0; i < 16; i++) s += pred[c][e][i];
        Vg[((size_t)(nh * CC + c0 + c)) * EE + e] = s;
    }
}

// ---------------- K5: per-query top-32 re-attention + V_bottom ----------------
__global__ __launch_bounds__(256) void k_out(const float* __restrict__ Q,
                                             const float* __restrict__ Kp,
                                             const float* __restrict__ Vp,
                                             const int* __restrict__ clusters,
                                             const int* __restrict__ topi,
                                             const float* __restrict__ abk,
                                             const float* __restrict__ Vg,
                                             float* __restrict__ out) {
    int tid = threadIdx.x, wid = tid >> 6, e = tid & 63;
    int q = blockIdx.x * 4 + wid;            // nh*LQ + l
    int nh = q >> 11, l = q & (LQ - 1);
    int n = nh >> 3, h = nh & 7;
    int c = clusters[q];
    float scale = 1.0f - abk[nh * CC + c];
    const int* ti = topi + (size_t)(nh * CC + c) * TK;
    float qe = Q[(((size_t)n * LQ + l) * HH + h) * EE + e];
    float myv = -INFINITY;
    for (int k = 0; k < TK; k++) {
        int idx = ti[k];
        float kv = Kp[(((size_t)n * SS + idx) * HH + h) * EE + e];
        float v = qe * kv;
        #pragma unroll
        for (int o = 32; o > 0; o >>= 1) v += __shfl_xor(v, o);
        if (e == k) myv = v;
    }
    float mv = myv;
    #pragma unroll
    for (int o = 32; o > 0; o >>= 1) { float v = __shfl_xor(mv, o); mv = v > mv ? v : mv; }
    float p = (e < TK) ? expf(0.125f * (myv - mv)) : 0.0f;
    float ssum = p;
    #pragma unroll
    for (int o = 32; o > 0; o >>= 1) ssum += __shfl_xor(ssum, o);
    float at = p / ssum * scale;
    float acc = 0.0f;
    for (int k = 0; k < TK; k++) {
        float wk = __shfl(at, k, 64);
        int idx = ti[k];
        acc += wk * Vp[(((size_t)n * SS + idx) * HH + h) * EE + e];
    }
    acc += Vg[(size_t)(nh * CC + c) * EE + e];
    out[(((size_t)n * LQ + l) * HH + h) * EE + e] = acc;
}

extern "C" void kernel_launch(void* const* d_in, const int* in_sizes, int n_in,
                              void* d_out, int out_size, void* d_ws, size_t ws_size,
                              hipStream_t stream) {
    const float* Q      = (const float*)d_in[0];
    const float* K      = (const float*)d_in[1];
    const float* V      = (const float*)d_in[2];
    const float* planes = (const float*)d_in[3];
    float* out = (float*)d_out;

    char* ws = (char*)d_ws;
    unsigned int* qmask    = (unsigned int*)(ws);                   // 128KB
    int*          clusters = (int*)(ws + (128 << 10));              // 128KB (= asg)
    int*          counts   = (int*)(ws + (256 << 10));              // 16KB
    float*        abk      = (float*)(ws + (272 << 10));            // 16KB
    int*          topi     = (int*)(ws + (288 << 10));              // 512KB
    float*        Vg       = (float*)(ws + (800 << 10));            // 1MB
    double*       Qg       = (double*)(ws + (1824 << 10));          // 2MB
    float*        Kt       = (float*)(ws + (4096 << 10));           // 8MB  [4MB,12MB)
    int*          order    = (int*)(ws + (12288 << 10));            // 128KB
    int*          offsets  = (int*)(ws + (12416 << 10));            // 16KB
    unsigned int* cent_g   = (unsigned int*)(ws + (12432 << 10));   // 16KB
    float*        Vt       = (float*)(ws + (12544 << 10));          // 8MB [12.25MB,20.25MB)

    k_transpose<<<dim3(NH * 32), dim3(256), 0, stream>>>(K, Kt);
    k_transpose<<<dim3(NH * 32), dim3(256), 0, stream>>>(V, Vt);
    k_hash<<<dim3(NH * LQ / 256), dim3(256), 0, stream>>>(Q, planes, qmask);
    k_cinit<<<dim3(NH), dim3(256), 0, stream>>>(qmask, cent_g);
    for (int it = 0; it < KM_ITERS; ++it) {
        k_assign<<<dim3(NH * 8), dim3(256), 0, stream>>>(qmask, cent_g, clusters);
        k_update<<<dim3(NH), dim3(512), 0, stream>>>(qmask, clusters, cent_g);
    }
    k_assign<<<dim3(NH * 8), dim3(256), 0, stream>>>(qmask, cent_g, clusters);
    k_finalize<<<dim3(NH), dim3(512), 0, stream>>>(clusters, counts, order, offsets);
    k_qg<<<dim3(NH * 64), dim3(256), 0, stream>>>(Q, order, offsets, counts, Qg);
    k_rows<<<dim3(NH * CC / CG), dim3(256), 0, stream>>>(Kt, Vt, Qg, topi, abk, Vg);
    k_out<<<dim3(NH * LQ / 4), dim3(256), 0, stream>>>(Q, K, V, clusters, topi, abk, Vg, out);
}